// Round 15
// baseline (147.074 us; speedup 1.0000x reference)
//
#include <hip/hip_runtime.h>

// WeightedAggregator: out[n,:] = sum_{e in seg(n)} eff_w[e]*feat[nidx[e],:] / den[n]
//   wsum[n] = sum of edge_weights in segment n (segment_ids sorted)
//   use_mean = (wsum == 0) -> eff_w = 1, den = deg; else eff_w = w, den = wsum
//   den == 0 -> 1 (empty nodes output zeros)
//
// R8 post-mortem: 62us, BW 41%, VALU 36% -> DS pipe (ds_bpermute from __shfl)
// is the serializer: ~22 bpermutes/wave ~ 21us of DS occupancy + dependent
// chains on the critical path.
// R9: quarter-wave (16 lanes x float4 = one row) per node -> ZERO cross-lane
// ops. ws accumulated identically by all 16 lanes (broadcast loads); dual
// accumulators (weighted + unweighted) defer the use_mean select to the end.
// Unroll-4 keeps 4 independent 1KB gathers in flight per wave.

#define D_FEAT 64

// ---- Pass 1: offs[v] = lower_bound(seg, v), v in [0, N] -------------------
__global__ __launch_bounds__(256) void WA_build_offsets_kernel(
        const int* __restrict__ seg, int* __restrict__ offs, int N, int E) {
    const int tid = blockIdx.x * blockDim.x + threadIdx.x;
    if (tid > E) return;
    const int cur  = (tid == E) ? N : seg[tid];
    const int prev = (tid == 0) ? -1 : seg[tid - 1];
    // Only boundary threads loop; avg trip = N/E + 1 ~ 1.06.
    for (int v = prev + 1; v <= cur; ++v) offs[v] = tid;
}

// ---- Pass 2: one quarter-wave per node ------------------------------------
__global__ __launch_bounds__(256) void WeightedAggregator_28424093564968_kernel(
        const float* __restrict__ feat,   // [N, 64]
        const float* __restrict__ ew,     // [E]
        const int*   __restrict__ nidx,   // [E]
        const int*   __restrict__ offs,   // [N+1]
        float*       __restrict__ out,    // [N, 64]
        int N) {
    const int gwave = (blockIdx.x * blockDim.x + threadIdx.x) >> 6;
    const int lane  = threadIdx.x & 63;
    const int slot  = lane >> 4;          // quarter id: which node of the 4
    const int dofs  = (lane & 15) << 2;   // this lane's feature dims

    const int  n  = gwave * 4 + slot;
    const bool vn = n < N;

    // Per-quarter uniform range (1-2 cache lines per wave instruction).
    const int start = vn ? offs[n]     : 0;
    const int end   = vn ? offs[n + 1] : 0;
    const int deg   = end - start;

    float ws = 0.0f;  // replicated identically across the 16 lanes
    float awx = 0.f, awy = 0.f, awz = 0.f, aww = 0.f;   // weighted sum
    float aux = 0.f, auy = 0.f, auz = 0.f, auw = 0.f;   // unweighted sum

    for (int k = 0; __any(k < deg); k += 4) {
        #pragma unroll
        for (int j = 0; j < 4; ++j) {
            const int  kk = k + j;
            const bool v  = kk < deg;
            const int  e  = v ? (start + kk) : 0;     // clamp: no OOB
            const int  id = v ? nidx[e] : 0;          // 16-lane broadcast load
            const float w = v ? ew[e]   : 0.0f;       // 16-lane broadcast load
            const float s = v ? 1.0f    : 0.0f;
            const float4 f = *(const float4*)(feat + (size_t)id * D_FEAT + dofs);
            ws  += w;
            awx += w * f.x; awy += w * f.y; awz += w * f.z; aww += w * f.w;
            aux += s * f.x; auy += s * f.y; auz += s * f.z; auw += s * f.w;
        }
    }

    // ws identical across the quarter's lanes -> uniform decision, no reduce.
    const bool use_mean = (ws == 0.0f);
    float den = use_mean ? (float)deg : ws;
    if (den == 0.0f) den = 1.0f;
    const float inv = 1.0f / den;

    if (vn) {
        float4 r;
        r.x = (use_mean ? aux : awx) * inv;
        r.y = (use_mean ? auy : awy) * inv;
        r.z = (use_mean ? auz : awz) * inv;
        r.w = (use_mean ? auw : aww) * inv;
        *(float4*)(out + (size_t)n * D_FEAT + dofs) = r;  // 64B per quarter
    }
}

// ---- Fallback (ws too small): R6's search-based kernel --------------------
__global__ __launch_bounds__(256) void WA_search_kernel(
        const float* __restrict__ feat, const float* __restrict__ ew,
        const int* __restrict__ nidx, const int* __restrict__ seg,
        float* __restrict__ out, int N, int E) {
    const int wave = (blockIdx.x * blockDim.x + threadIdx.x) >> 6;
    const int lane = threadIdx.x & 63;
    if (wave >= N) return;
    const int n = wave;

    int lo = 0, hi = E;
    while (hi - lo > 64) {
        const long long span = hi - lo;
        const int p = lo + (int)((span * (lane + 1)) / 65);
        const bool ge = seg[p] >= n;
        const unsigned long long mask = __ballot(ge);
        if (mask == 0ull) {
            lo = lo + (int)((span * 64) / 65);
        } else {
            const int first = __ffsll((long long)mask) - 1;
            const int nhi = lo + (int)((span * (first + 1)) / 65);
            const int nlo = (first == 0) ? lo : lo + (int)((span * first) / 65);
            lo = nlo; hi = nhi;
        }
    }
    {
        const int p = lo + lane;
        const bool ge = (p >= hi) || (seg[p] >= n);
        const unsigned long long mask = __ballot(ge);
        lo = (mask == 0ull) ? hi : lo + __ffsll((long long)mask) - 1;
    }
    const int start = lo;
    int end = start;
    for (;;) {
        const int p = end + lane;
        const bool stop = (p >= E) || (seg[p] > n);
        const unsigned long long mask = __ballot(stop);
        if (mask) { end += __ffsll((long long)mask) - 1; break; }
        end += 64;
    }

    float ws = 0.0f;
    for (int e = start + lane; e < end; e += 64) ws += ew[e];
    #pragma unroll
    for (int off = 32; off > 0; off >>= 1) ws += __shfl_xor(ws, off);
    const bool use_mean = (ws == 0.0f);
    float den = use_mean ? (float)(end - start) : ws;
    if (den == 0.0f) den = 1.0f;

    const int slot = lane >> 4;
    const int dofs = (lane & 15) << 2;
    float ax = 0.f, ay = 0.f, az = 0.f, aw = 0.f;
    for (int e = start; e < end; e += 8) {
        const int p0 = e + slot, p1 = e + 4 + slot;
        const bool v0 = p0 < end, v1 = p1 < end;
        const int  i0 = v0 ? nidx[p0] : 0;
        const int  i1 = v1 ? nidx[p1] : 0;
        const float w0 = v0 ? (use_mean ? 1.0f : ew[p0]) : 0.0f;
        const float w1 = v1 ? (use_mean ? 1.0f : ew[p1]) : 0.0f;
        const float4 f0 = *(const float4*)(feat + (size_t)i0 * D_FEAT + dofs);
        const float4 f1 = *(const float4*)(feat + (size_t)i1 * D_FEAT + dofs);
        ax += w0 * f0.x; ay += w0 * f0.y; az += w0 * f0.z; aw += w0 * f0.w;
        ax += w1 * f1.x; ay += w1 * f1.y; az += w1 * f1.z; aw += w1 * f1.w;
    }
    #pragma unroll
    for (int m = 16; m <= 32; m <<= 1) {
        ax += __shfl_xor(ax, m); ay += __shfl_xor(ay, m);
        az += __shfl_xor(az, m); aw += __shfl_xor(aw, m);
    }
    if (slot == 0) {
        const float inv = 1.0f / den;
        float4 r; r.x = ax*inv; r.y = ay*inv; r.z = az*inv; r.w = aw*inv;
        *(float4*)(out + (size_t)n * D_FEAT + dofs) = r;
    }
}

extern "C" void kernel_launch(void* const* d_in, const int* in_sizes, int n_in,
                              void* d_out, int out_size, void* d_ws, size_t ws_size,
                              hipStream_t stream) {
    const float* feat = (const float*)d_in[0];
    const float* ew   = (const float*)d_in[1];
    const int*   nidx = (const int*)d_in[2];
    const int*   seg  = (const int*)d_in[3];
    float*       out  = (float*)d_out;

    const int E = in_sizes[1];
    const int N = in_sizes[0] / D_FEAT;

    if (ws_size >= (size_t)(N + 1) * sizeof(int)) {
        int* offs = (int*)d_ws;
        const int g1 = (E + 1 + 255) / 256;
        WA_build_offsets_kernel<<<g1, 256, 0, stream>>>(seg, offs, N, E);
        // 4 nodes per wave, 4 waves per block -> 16 nodes per block.
        const int nodes_per_block = 16;
        const int grid = (N + nodes_per_block - 1) / nodes_per_block;
        WeightedAggregator_28424093564968_kernel<<<grid, 256, 0, stream>>>(
            feat, ew, nidx, offs, out, N);
    } else {
        const int grid = (N + 3) / 4;
        WA_search_kernel<<<grid, 256, 0, stream>>>(feat, ew, nidx, seg, out, N, E);
    }
}